// Round 4
// baseline (139.850 us; speedup 1.0000x reference)
//
#include <hip/hip_runtime.h>

#define NPIX   1024
#define BATCH  16
#define CIN    256
#define NQKV   1536
#define INNER  512
#define HEADS  8
#define DH     64

typedef __attribute__((ext_vector_type(8))) short short8;   // 8 bf16 = 4 VGPRs
typedef __attribute__((ext_vector_type(4))) float f32x4;

__device__ __forceinline__ ushort f2b(float f) {
    union { float f; unsigned u; } v; v.f = f;
    unsigned r = v.u + 0x7fffu + ((v.u >> 16) & 1u);   // RNE
    return (ushort)(r >> 16);
}
__device__ __forceinline__ float b2f(ushort u) {
    union { float f; unsigned u; } v; v.u = ((unsigned)u) << 16; return v.f;
}
__device__ __forceinline__ void async16(const void* g, void* l) {
    __builtin_amdgcn_global_load_lds((const __attribute__((address_space(1))) void*)g,
                                     (__attribute__((address_space(3))) void*)l, 16, 0, 0);
}

// ---------------------------------------------------------------------------
// prep_x: x [b][c][p] f32 -> xT [b][p][c] bf16  (transpose + convert)
// ---------------------------------------------------------------------------
__global__ __launch_bounds__(256) void prep_x(const float* __restrict__ x,
                                              ushort* __restrict__ xT) {
    __shared__ float tile[32][33];
    const int b  = blockIdx.z;
    const int p0 = blockIdx.x * 32;
    const int c0 = blockIdx.y * 32;
    const int tx = threadIdx.x, ty = threadIdx.y;   // 32 x 8
#pragma unroll
    for (int i = 0; i < 4; i++) {
        int c = ty + i * 8;
        tile[c][tx] = x[(b * CIN + c0 + c) * NPIX + p0 + tx];
    }
    __syncthreads();
#pragma unroll
    for (int i = 0; i < 4; i++) {
        int p = ty + i * 8;
        xT[(b * NPIX + p0 + p) * CIN + c0 + tx] = f2b(tile[tx][p]);
    }
}

// ---------------------------------------------------------------------------
// prep_w: Wq/Wkv -> Wqkv_b [1536][256] bf16 (k-minor); Wo -> bf16
// ---------------------------------------------------------------------------
__global__ __launch_bounds__(256) void prep_w(const float* __restrict__ Wq,
        const float* __restrict__ Wkv, const float* __restrict__ Wo,
        ushort* __restrict__ Wqkv_b, ushort* __restrict__ Wob) {
    int i = blockIdx.x * 256 + threadIdx.x;
    if (i < NQKV * CIN)
        Wqkv_b[i] = f2b(i < INNER * CIN ? Wq[i] : Wkv[i - INNER * CIN]);
    int j = i - NQKV * CIN;
    if (j >= 0 && j < CIN * INNER)
        Wob[j] = f2b(Wo[j]);
}

// ---------------------------------------------------------------------------
// GEMM1 (MFMA, 2-phase dbuf): D[o][p] = sum_c Wqkv_b[o][c] * xT[p][c]
// Flat grid of 1536 blocks, XCD-chunked: each XCD gets 16 contiguous
// m-tiles x all 12 o-tiles (W + 16 xT tiles ~ 1.8MB -> L2-resident).
// ---------------------------------------------------------------------------
__global__ __launch_bounds__(256) void gemm_qkv(const ushort* __restrict__ xT,
        const ushort* __restrict__ Wb, ushort* __restrict__ qkv) {
    __shared__ ushort As[2][128][32];   // rows = o
    __shared__ ushort Bs[2][128][32];   // rows = p
    const int bid = blockIdx.x;
    const int swz = (bid & 7) * 192 + (bid >> 3);   // 1536 = 8 XCD * 192
    const int m0  = (swz / 12) * 128;               // pixel tile
    const int n0  = (swz % 12) * 128;               // o tile
    const int t    = threadIdx.x;
    const int wave = t >> 6, lane = t & 63;
    const int wo = (wave & 1) * 64, wp = (wave >> 1) * 64;
    const int lrow = lane & 15, loct = lane >> 4;

    const int srow = t >> 2;            // staging row (0..63)
    const int skb  = (t & 3) * 8;       // staging k offset (ushorts)
    const ushort* gA = Wb + (n0 + srow) * CIN + skb;
    const ushort* gB = xT + (m0 + srow) * CIN + skb;

    f32x4 acc[4][4];
#pragma unroll
    for (int i = 0; i < 4; i++)
#pragma unroll
        for (int j = 0; j < 4; j++) acc[i][j] = (f32x4){0.f, 0.f, 0.f, 0.f};

#define STAGE1(buf, c0)                                             \
    do {                                                            \
        async16(gA + (c0),            &As[buf][wave * 16][0]);      \
        async16(gA + 64 * CIN + (c0), &As[buf][64 + wave * 16][0]); \
        async16(gB + (c0),            &Bs[buf][wave * 16][0]);      \
        async16(gB + 64 * CIN + (c0), &Bs[buf][64 + wave * 16][0]); \
    } while (0)

    STAGE1(0, 0);
    __syncthreads();                       // prologue: buf0 ready
    int cur = 0;
    const int NT = CIN / 32;               // 8
    for (int it = 0; it < NT; ++it) {
        if (it + 1 < NT) STAGE1(cur ^ 1, (it + 1) * 32);   // issue next first
        short8 a[4], bb[4];
#pragma unroll
        for (int i = 0; i < 4; i++)
            a[i] = *reinterpret_cast<const short8*>(&As[cur][wo + i * 16 + lrow][loct * 8]);
#pragma unroll
        for (int j = 0; j < 4; j++)
            bb[j] = *reinterpret_cast<const short8*>(&Bs[cur][wp + j * 16 + lrow][loct * 8]);
#pragma unroll
        for (int i = 0; i < 4; i++)
#pragma unroll
            for (int j = 0; j < 4; j++)
                acc[i][j] = __builtin_amdgcn_mfma_f32_16x16x32_bf16(a[i], bb[j], acc[i][j], 0, 0, 0);
        __syncthreads();                   // drains this iter's stage; next buf ready
        cur ^= 1;
    }
#undef STAGE1

#pragma unroll
    for (int i = 0; i < 4; i++)
#pragma unroll
        for (int j = 0; j < 4; j++) {
            int gm = m0 + wp + j * 16 + lrow;
            int go = n0 + wo + i * 16 + loct * 4;
            ushort4 pk = make_ushort4(f2b(acc[i][j].x), f2b(acc[i][j].y),
                                      f2b(acc[i][j].z), f2b(acc[i][j].w));
            *reinterpret_cast<ushort4*>(&qkv[gm * NQKV + go]) = pk;
        }
}

// ---------------------------------------------------------------------------
// Attention: one wave per pixel m; lane = (h, d-octet). XCD-chunked block
// swizzle keeps each XCD's pixel range (and its 3x3 k/v halo) in its own L2.
// ---------------------------------------------------------------------------
__global__ __launch_bounds__(256) void attn_kernel(const ushort* __restrict__ qkv,
        ushort* __restrict__ po, float* __restrict__ attn_out) {
    const int bid = blockIdx.x;
    const int swz = (bid & 7) * 512 + (bid >> 3);   // 4096 = 8 XCD * 512
    const int m    = swz * 4 + (threadIdx.x >> 6);
    const int lane = threadIdx.x & 63;
    const int h = lane >> 3, sub = lane & 7;
    const int b = m >> 10;
    const int p = m & 1023;
    const int py = p >> 5, px = p & 31;
    const int hd8 = h * DH + sub * 8;

    short8 qv = *reinterpret_cast<const short8*>(&qkv[m * NQKV + hd8]);
    float qf[8];
#pragma unroll
    for (int j = 0; j < 8; j++) qf[j] = b2f((ushort)qv[j]);

    float dots[9];
    int   nb[9];
    bool  ok[9];
#pragma unroll
    for (int w = 0; w < 9; w++) {
        int dy = w / 3 - 1, dx = w % 3 - 1;
        int ny = py + dy, nx = px + dx;
        bool in = ((unsigned)ny < 32u) && ((unsigned)nx < 32u);
        ok[w] = in;
        int nm = b * NPIX + ny * 32 + nx;
        nb[w] = nm;
        float d = 0.f;
        if (in) {
            short8 kv8 = *reinterpret_cast<const short8*>(&qkv[nm * NQKV + 512 + hd8]);
#pragma unroll
            for (int j = 0; j < 8; j++) d = fmaf(qf[j], b2f((ushort)kv8[j]), d);
        }
        d += __shfl_xor(d, 1);
        d += __shfl_xor(d, 2);
        d += __shfl_xor(d, 4);
        dots[w] = d * 0.125f;   // OOB: exact 0 (zero-pad semantics)
    }

    float mx = dots[0];
#pragma unroll
    for (int w = 1; w < 9; w++) mx = fmaxf(mx, dots[w]);
    float e[9], s = 0.f;
#pragma unroll
    for (int w = 0; w < 9; w++) { e[w] = __expf(dots[w] - mx); s += e[w]; }
    const float inv = 1.f / s;

    float o[8] = {};
#pragma unroll
    for (int w = 0; w < 9; w++) {
        if (ok[w]) {
            short8 vv = *reinterpret_cast<const short8*>(&qkv[nb[w] * NQKV + 1024 + hd8]);
            float pw = e[w] * inv;
#pragma unroll
            for (int j = 0; j < 8; j++) o[j] = fmaf(pw, b2f((ushort)vv[j]), o[j]);
        }
    }
    short8 r;
#pragma unroll
    for (int j = 0; j < 8; j++) r[j] = (short)f2b(o[j]);
    *reinterpret_cast<short8*>(&po[m * INNER + hd8]) = r;

    float* ab = &attn_out[((b * HEADS + h) * NPIX + p) * 9];
    ab[sub] = e[sub] * inv;
    if (sub == 0) ab[8] = e[8] * inv;
}

// ---------------------------------------------------------------------------
// GEMM2 (MFMA, 2-phase dbuf): D[p][o] = sum_i po[p][i] * Wob[o][i]  (+ bias)
// ---------------------------------------------------------------------------
__global__ __launch_bounds__(256) void gemm_out(const ushort* __restrict__ po,
        const ushort* __restrict__ Wob, const float* __restrict__ bo,
        float* __restrict__ out) {
    __shared__ ushort As[2][128][32];   // rows = p
    __shared__ ushort Bs[2][128][32];   // rows = o
    const int m0 = blockIdx.x * 128;
    const int n0 = blockIdx.y * 128;
    const int t    = threadIdx.x;
    const int wave = t >> 6, lane = t & 63;
    const int wm = (wave >> 1) * 64, wn = (wave & 1) * 64;
    const int lrow = lane & 15, loct = lane >> 4;

    const int srow = t >> 2;
    const int skb  = (t & 3) * 8;
    const ushort* gA = po  + (m0 + srow) * INNER + skb;
    const ushort* gB = Wob + (n0 + srow) * INNER + skb;

    f32x4 acc[4][4];
#pragma unroll
    for (int i = 0; i < 4; i++)
#pragma unroll
        for (int j = 0; j < 4; j++) acc[i][j] = (f32x4){0.f, 0.f, 0.f, 0.f};

#define STAGE2(buf, c0)                                               \
    do {                                                              \
        async16(gA + (c0),              &As[buf][wave * 16][0]);      \
        async16(gA + 64 * INNER + (c0), &As[buf][64 + wave * 16][0]); \
        async16(gB + (c0),              &Bs[buf][wave * 16][0]);      \
        async16(gB + 64 * INNER + (c0), &Bs[buf][64 + wave * 16][0]); \
    } while (0)

    STAGE2(0, 0);
    __syncthreads();
    int cur = 0;
    const int NT = INNER / 32;             // 16
    for (int it = 0; it < NT; ++it) {
        if (it + 1 < NT) STAGE2(cur ^ 1, (it + 1) * 32);
        short8 a[4], bb[4];
#pragma unroll
        for (int i = 0; i < 4; i++)
            a[i] = *reinterpret_cast<const short8*>(&As[cur][wm + i * 16 + lrow][loct * 8]);
#pragma unroll
        for (int j = 0; j < 4; j++)
            bb[j] = *reinterpret_cast<const short8*>(&Bs[cur][wn + j * 16 + lrow][loct * 8]);
#pragma unroll
        for (int i = 0; i < 4; i++)
#pragma unroll
            for (int j = 0; j < 4; j++)
                acc[i][j] = __builtin_amdgcn_mfma_f32_16x16x32_bf16(a[i], bb[j], acc[i][j], 0, 0, 0);
        __syncthreads();
        cur ^= 1;
    }
#undef STAGE2

    const int bb_ = m0 >> 10;
    const int p0  = m0 & 1023;
#pragma unroll
    for (int i = 0; i < 4; i++)
#pragma unroll
        for (int j = 0; j < 4; j++) {
            int o  = n0 + wn + j * 16 + lrow;
            int pp = p0 + wm + i * 16 + loct * 4;
            float bias = bo[o];
            float4 v = make_float4(acc[i][j].x + bias, acc[i][j].y + bias,
                                   acc[i][j].z + bias, acc[i][j].w + bias);
            *reinterpret_cast<float4*>(&out[(bb_ * CIN + o) * NPIX + pp]) = v;
        }
}

// ---------------------------------------------------------------------------
extern "C" void kernel_launch(void* const* d_in, const int* in_sizes, int n_in,
                              void* d_out, int out_size, void* d_ws, size_t ws_size,
                              hipStream_t stream) {
    const float* x   = (const float*)d_in[0];
    const float* Wq  = (const float*)d_in[1];
    const float* Wkv = (const float*)d_in[2];
    const float* Wo  = (const float*)d_in[3];
    const float* bo  = (const float*)d_in[4];

    float* out  = (float*)d_out;
    float* attn = out + BATCH * CIN * NPIX;

    ushort* xT     = (ushort*)d_ws;               // 16384*256
    ushort* Wqkv_b = xT + 16384 * CIN;            // 1536*256
    ushort* Wob    = Wqkv_b + NQKV * CIN;         // 256*512
    ushort* qkv    = Wob + CIN * INNER;           // 16384*1536
    ushort* po     = qkv + 16384 * NQKV;          // 16384*512

    prep_x<<<dim3(32, 8, BATCH), dim3(32, 8), 0, stream>>>(x, xT);
    prep_w<<<2048, 256, 0, stream>>>(Wq, Wkv, Wo, Wqkv_b, Wob);

    gemm_qkv<<<1536, 256, 0, stream>>>(xT, Wqkv_b, qkv);

    attn_kernel<<<16384 / 4, 256, 0, stream>>>(qkv, po, attn);

    gemm_out<<<dim3(128, 2), 256, 0, stream>>>(po, Wob, bo, out);
}